// Round 1
// baseline (140.175 us; speedup 1.0000x reference)
//
#include <hip/hip_runtime.h>

#define B_ 8
#define T_ 4096
#define D_ 128
#define H_ 64

typedef short bf16x8 __attribute__((ext_vector_type(8)));
typedef float f32x4 __attribute__((ext_vector_type(4)));

__device__ __forceinline__ unsigned short f2bf(float f) {
  unsigned int u = __float_as_uint(f);
  u += 0x7fffu + ((u >> 16) & 1u);   // RNE
  return (unsigned short)(u >> 16);
}

// ---- workspace layout (bytes) ----
#define OFF_XP  0u
#define SZ_XP   ((unsigned)(B_*(T_+2)*D_*2))      // padded bf16 X, zero rows at batch edges
#define OFF_XT  (OFF_XP + SZ_XP)
#define SZ_XT   ((unsigned)(B_*D_*T_*2))          // V^T bf16 [B][128][T]
#define OFF_F   (OFF_XT + SZ_XT)
#define SZ_F    ((unsigned)(B_*T_*H_*2))
#define OFF_G   (OFF_F + SZ_F)
#define OFF_WFT (OFF_G + SZ_F)
#define SZ_WFT  ((unsigned)(H_*D_*2))
#define OFF_WGT (OFF_WFT + SZ_WFT)

#define SWZ(off, r) ((off) ^ (((r) & 7) << 4))

// ---------------- kernel 1: cast X -> Xp (padded bf16) and transpose -> XT ----------------
__global__ __launch_bounds__(256) void prep_x(const float* __restrict__ X,
                                              unsigned short* __restrict__ Xp,
                                              unsigned short* __restrict__ XT) {
  __shared__ unsigned short tile[64][129];   // +1 pad: conflict-free column reads
  const int b = blockIdx.x;
  const int t0 = blockIdx.y * 64;
  const int tid = threadIdx.x;
#pragma unroll
  for (int c = 0; c < 8; ++c) {
    int i4 = tid + c * 256;               // 0..2047 float4 chunks of the 64x128 tile
    int row = i4 >> 5, col4 = i4 & 31;
    float4 v = ((const float4*)X)[(size_t)(b * T_ + t0 + row) * 32 + col4];
    ushort4 h;
    h.x = f2bf(v.x); h.y = f2bf(v.y); h.z = f2bf(v.z); h.w = f2bf(v.w);
    ((ushort4*)Xp)[(size_t)(b * (T_ + 2) + 1 + t0 + row) * 32 + col4] = h;
    tile[row][col4 * 4 + 0] = h.x;
    tile[row][col4 * 4 + 1] = h.y;
    tile[row][col4 * 4 + 2] = h.z;
    tile[row][col4 * 4 + 3] = h.w;
  }
  if (blockIdx.y == 0 && tid < 32) {       // zero pad rows (conv boundary)
    ushort4 z = {0, 0, 0, 0};
    ((ushort4*)Xp)[(size_t)(b * (T_ + 2) + 0) * 32 + tid] = z;
    ((ushort4*)Xp)[(size_t)(b * (T_ + 2) + T_ + 1) * 32 + tid] = z;
  }
  __syncthreads();
#pragma unroll
  for (int c = 0; c < 8; ++c) {
    int o4 = tid + c * 256;               // 0..2047 ushort4 chunks of XT tile
    int d = o4 >> 4, t4 = o4 & 15;
    ushort4 h;
    h.x = tile[t4 * 4 + 0][d];
    h.y = tile[t4 * 4 + 1][d];
    h.z = tile[t4 * 4 + 2][d];
    h.w = tile[t4 * 4 + 3][d];
    ((ushort4*)XT)[(size_t)(b * 128 + d) * (T_ / 4) + (t0 >> 2) + t4] = h;
  }
}

// ---------------- kernel 2: weights -> transposed bf16 (Wf pre-scaled by log2e/8) ----------------
__global__ __launch_bounds__(256) void prep_w(const float* __restrict__ Wf,
                                              const float* __restrict__ Wg,
                                              unsigned short* __restrict__ WfT,
                                              unsigned short* __restrict__ WgT) {
  const float SC = 0.18033688011112042f;  // (1/sqrt(64)) * log2(e)
  int idx = blockIdx.x * 256 + threadIdx.x;    // 0..32767
  if (idx < H_ * D_) {
    int h = idx >> 7, d = idx & 127;
    WfT[idx] = f2bf(Wf[d * H_ + h] * SC);
  } else {
    int j = idx - H_ * D_;                     // 0..24575
    int tap = j >> 13, r = j & 8191;
    int h = r >> 7, d = r & 127;
    WgT[j] = f2bf(Wg[tap * (D_ * H_) + d * H_ + h]);
  }
}

// ---------------- kernel 3: F = Xp[t+1]*Wf (pre-scaled), G = sum_taps Xp[t+s]*Wg[s] ----------------
__global__ __launch_bounds__(64) void fg_kernel(const unsigned short* __restrict__ Xp,
                                                const unsigned short* __restrict__ WfT,
                                                const unsigned short* __restrict__ WgT,
                                                unsigned short* __restrict__ F,
                                                unsigned short* __restrict__ G) {
  const int lane = threadIdx.x;
  const int rowbase = blockIdx.x * 64;         // global (b,t) row
  const int b = rowbase >> 12, t0 = rowbase & (T_ - 1);
  const int l15 = lane & 15, lhi = lane >> 4;
  const f32x4 fz = {0.f, 0.f, 0.f, 0.f};
  f32x4 accF[4][4], accG[4][4];
#pragma unroll
  for (int mt = 0; mt < 4; ++mt)
#pragma unroll
    for (int nt = 0; nt < 4; ++nt) { accF[mt][nt] = fz; accG[mt][nt] = fz; }

  for (int kk = 0; kk < 4; ++kk) {
    const int k0 = kk * 32 + lhi * 8;
    bf16x8 a[3][4];
#pragma unroll
    for (int sh = 0; sh < 3; ++sh)
#pragma unroll
      for (int mt = 0; mt < 4; ++mt) {
        int r = b * (T_ + 2) + t0 + sh + mt * 16 + l15;
        a[sh][mt] = *(const bf16x8*)&Xp[(size_t)r * 128 + k0];
      }
#pragma unroll
    for (int nt = 0; nt < 4; ++nt) {
      int h = nt * 16 + l15;
      bf16x8 wf  = *(const bf16x8*)&WfT[h * 128 + k0];
      bf16x8 wg0 = *(const bf16x8*)&WgT[(0 * 64 + h) * 128 + k0];
      bf16x8 wg1 = *(const bf16x8*)&WgT[(1 * 64 + h) * 128 + k0];
      bf16x8 wg2 = *(const bf16x8*)&WgT[(2 * 64 + h) * 128 + k0];
#pragma unroll
      for (int mt = 0; mt < 4; ++mt) {
        accF[mt][nt] = __builtin_amdgcn_mfma_f32_16x16x32_bf16(a[1][mt], wf,  accF[mt][nt], 0, 0, 0);
        accG[mt][nt] = __builtin_amdgcn_mfma_f32_16x16x32_bf16(a[0][mt], wg0, accG[mt][nt], 0, 0, 0);
        accG[mt][nt] = __builtin_amdgcn_mfma_f32_16x16x32_bf16(a[1][mt], wg1, accG[mt][nt], 0, 0, 0);
        accG[mt][nt] = __builtin_amdgcn_mfma_f32_16x16x32_bf16(a[2][mt], wg2, accG[mt][nt], 0, 0, 0);
      }
    }
  }
#pragma unroll
  for (int mt = 0; mt < 4; ++mt)
#pragma unroll
    for (int nt = 0; nt < 4; ++nt)
#pragma unroll
      for (int r = 0; r < 4; ++r) {
        int t = t0 + mt * 16 + lhi * 4 + r;
        int h = nt * 16 + l15;
        size_t o = (size_t)(b * T_ + t) * 64 + h;
        F[o] = f2bf(accF[mt][nt][r]);
        G[o] = f2bf(accG[mt][nt][r]);
      }
}

// ---------------- kernel 4: flash attention, Q=F K=G V=X, P=exp2(S) (no max tracking) ----------------
__global__ __launch_bounds__(256) void attn_kernel(const unsigned short* __restrict__ F,
                                                   const unsigned short* __restrict__ G,
                                                   const unsigned short* __restrict__ XT,
                                                   float* __restrict__ out) {
  __shared__ unsigned short klds[64 * 64];       // 8KB,  [s][h] swizzled
  __shared__ unsigned short vlds[128 * 64];      // 16KB, [d][s] swizzled (V^T tile)
  __shared__ unsigned short plds[4][32 * 64];    // 16KB, per-wave [q][s] swizzled
  const int b = blockIdx.x;
  const int q0 = blockIdx.y * 128;
  const int tid = threadIdx.x;
  const int wave = tid >> 6, lane = tid & 63;
  const int l15 = lane & 15, lhi = lane >> 4;
  const int qw = q0 + wave * 32;

  bf16x8 qf[2][2];
#pragma unroll
  for (int mt = 0; mt < 2; ++mt)
#pragma unroll
    for (int kk = 0; kk < 2; ++kk)
      qf[mt][kk] = *(const bf16x8*)&F[(size_t)(b * T_ + qw + mt * 16 + l15) * 64 + kk * 32 + lhi * 8];

  const f32x4 fz = {0.f, 0.f, 0.f, 0.f};
  f32x4 o_acc[2][8];
  f32x4 sacc[2];
#pragma unroll
  for (int mt = 0; mt < 2; ++mt) {
    sacc[mt] = fz;
#pragma unroll
    for (int nt = 0; nt < 8; ++nt) o_acc[mt][nt] = fz;
  }
  bf16x8 ones;
#pragma unroll
  for (int j = 0; j < 8; ++j) ones[j] = (short)0x3F80;   // bf16 1.0

  char* kbase = (char*)klds;
  char* vbase = (char*)vlds;
  char* pbase = (char*)plds[wave];

  for (int s0 = 0; s0 < T_; s0 += 64) {
    __syncthreads();
    // stage K tile (G rows s0..s0+63), 512 x 16B
#pragma unroll
    for (int i = 0; i < 2; ++i) {
      int chunk = tid + i * 256;
      int s = chunk >> 3, h8 = chunk & 7;
      uint4 v = *(const uint4*)&G[(size_t)(b * T_ + s0 + s) * 64 + h8 * 8];
      *(uint4*)(kbase + SWZ(s * 128 + h8 * 16, s)) = v;
    }
    // stage V^T tile (all 128 d-rows, s0..s0+63), 1024 x 16B
#pragma unroll
    for (int i = 0; i < 4; ++i) {
      int chunk = tid + i * 256;
      int d = chunk >> 3, s8 = chunk & 7;
      uint4 v = *(const uint4*)&XT[(size_t)(b * 128 + d) * T_ + s0 + s8 * 8];
      *(uint4*)(vbase + SWZ(d * 128 + s8 * 16, d)) = v;
    }
    __syncthreads();

    // S = Q*K^T  (pre-scaled into exp2 units)
    f32x4 S[2][4];
#pragma unroll
    for (int st = 0; st < 4; ++st) {
      int srow = st * 16 + l15;
      bf16x8 kf0 = *(const bf16x8*)(kbase + SWZ(srow * 128 + (lhi * 8) * 2, srow));
      bf16x8 kf1 = *(const bf16x8*)(kbase + SWZ(srow * 128 + (32 + lhi * 8) * 2, srow));
#pragma unroll
      for (int mt = 0; mt < 2; ++mt) {
        f32x4 s_ = fz;
        s_ = __builtin_amdgcn_mfma_f32_16x16x32_bf16(qf[mt][0], kf0, s_, 0, 0, 0);
        s_ = __builtin_amdgcn_mfma_f32_16x16x32_bf16(qf[mt][1], kf1, s_, 0, 0, 0);
        S[mt][st] = s_;
      }
    }
    // P = exp2(S) -> bf16 -> per-wave LDS (logits bounded; fixed-max softmax, scale cancels)
#pragma unroll
    for (int mt = 0; mt < 2; ++mt) {
      int q = mt * 16 + lhi * 4;
#pragma unroll
      for (int st = 0; st < 4; ++st) {
        int s = st * 16 + l15;
#pragma unroll
        for (int r = 0; r < 4; ++r) {
          float p = __builtin_amdgcn_exp2f(S[mt][st][r]);
          *(unsigned short*)(pbase + SWZ((q + r) * 128 + s * 2, (q + r))) = f2bf(p);
        }
      }
    }
    // reload P as A-fragments
    bf16x8 pa[2][2];
#pragma unroll
    for (int mt = 0; mt < 2; ++mt) {
      int prow = mt * 16 + l15;
#pragma unroll
      for (int ks = 0; ks < 2; ++ks)
        pa[mt][ks] = *(const bf16x8*)(pbase + SWZ(prow * 128 + (ks * 32 + lhi * 8) * 2, prow));
    }
    // row-sums via ones-fragment MFMA (accumulates l across all tiles)
#pragma unroll
    for (int mt = 0; mt < 2; ++mt) {
      sacc[mt] = __builtin_amdgcn_mfma_f32_16x16x32_bf16(pa[mt][0], ones, sacc[mt], 0, 0, 0);
      sacc[mt] = __builtin_amdgcn_mfma_f32_16x16x32_bf16(pa[mt][1], ones, sacc[mt], 0, 0, 0);
    }
    // O += P * V
#pragma unroll
    for (int nt = 0; nt < 8; ++nt) {
      int drow = nt * 16 + l15;
      bf16x8 vf0 = *(const bf16x8*)(vbase + SWZ(drow * 128 + (lhi * 8) * 2, drow));
      bf16x8 vf1 = *(const bf16x8*)(vbase + SWZ(drow * 128 + (32 + lhi * 8) * 2, drow));
#pragma unroll
      for (int mt = 0; mt < 2; ++mt) {
        o_acc[mt][nt] = __builtin_amdgcn_mfma_f32_16x16x32_bf16(pa[mt][0], vf0, o_acc[mt][nt], 0, 0, 0);
        o_acc[mt][nt] = __builtin_amdgcn_mfma_f32_16x16x32_bf16(pa[mt][1], vf1, o_acc[mt][nt], 0, 0, 0);
      }
    }
  }
  // epilogue: out = O / l  (fp32)
#pragma unroll
  for (int mt = 0; mt < 2; ++mt) {
#pragma unroll
    for (int r = 0; r < 4; ++r) {
      float inv = 1.0f / sacc[mt][r];
      int t = qw + mt * 16 + lhi * 4 + r;
#pragma unroll
      for (int nt = 0; nt < 8; ++nt)
        out[(size_t)(b * T_ + t) * 128 + nt * 16 + l15] = o_acc[mt][nt][r] * inv;
    }
  }
}

extern "C" void kernel_launch(void* const* d_in, const int* in_sizes, int n_in,
                              void* d_out, int out_size, void* d_ws, size_t ws_size,
                              hipStream_t stream) {
  (void)in_sizes; (void)n_in; (void)out_size; (void)ws_size;
  const float* X  = (const float*)d_in[0];
  const float* Wf = (const float*)d_in[1];
  const float* Wg = (const float*)d_in[2];
  float* out = (float*)d_out;
  char* ws = (char*)d_ws;
  unsigned short* Xp  = (unsigned short*)(ws + OFF_XP);
  unsigned short* XT  = (unsigned short*)(ws + OFF_XT);
  unsigned short* Fb  = (unsigned short*)(ws + OFF_F);
  unsigned short* Gb  = (unsigned short*)(ws + OFF_G);
  unsigned short* WfT = (unsigned short*)(ws + OFF_WFT);
  unsigned short* WgT = (unsigned short*)(ws + OFF_WGT);

  prep_x<<<dim3(B_, T_ / 64), 256, 0, stream>>>(X, Xp, XT);
  prep_w<<<(H_ * D_ * 4) / 256, 256, 0, stream>>>(Wf, Wg, WfT, WgT);
  fg_kernel<<<(B_ * T_) / 64, 64, 0, stream>>>(Xp, WfT, WgT, Fb, Gb);
  attn_kernel<<<dim3(B_, T_ / 128), 256, 0, stream>>>(Fb, Gb, XT, out);
}

// Round 2
// 124.507 us; speedup vs baseline: 1.1258x; 1.1258x over previous
//
#include <hip/hip_runtime.h>

#define B_ 8
#define T_ 4096
#define D_ 128
#define H_ 64
#define SBLK 64
#define NT (T_ / SBLK)

typedef short bf16x8 __attribute__((ext_vector_type(8)));
typedef float f32x4 __attribute__((ext_vector_type(4)));

__device__ __forceinline__ unsigned short f2bf(float f) {
  unsigned int u = __float_as_uint(f);
  u += 0x7fffu + ((u >> 16) & 1u);   // RNE
  return (unsigned short)(u >> 16);
}

__device__ __forceinline__ void async_copy16(const void* g, void* l) {
  __builtin_amdgcn_global_load_lds((const __attribute__((address_space(1))) void*)g,
                                   (__attribute__((address_space(3))) void*)l, 16, 0, 0);
}

// ---- workspace layout (bytes) ----
#define OFF_XP  0u
#define SZ_XP   ((unsigned)(B_*(T_+2)*D_*2))      // padded bf16 X, zero rows at batch edges
#define OFF_XT  (OFF_XP + SZ_XP)
#define SZ_XT   ((unsigned)(B_*D_*T_*2))          // V^T bf16 [B][128][T]
#define OFF_F   (OFF_XT + SZ_XT)
#define SZ_F    ((unsigned)(B_*T_*H_*2))
#define OFF_G   (OFF_F + SZ_F)
#define OFF_WFT (OFF_G + SZ_F)
#define SZ_WFT  ((unsigned)(H_*D_*2))
#define OFF_WGT (OFF_WFT + SZ_WFT)

#define SWZ(off, r) ((off) ^ (((r) & 7) << 4))

// ---------------- kernel 1: cast X -> Xp (padded bf16) and transpose -> XT ----------------
__global__ __launch_bounds__(256) void prep_x(const float* __restrict__ X,
                                              unsigned short* __restrict__ Xp,
                                              unsigned short* __restrict__ XT) {
  __shared__ unsigned short tile[64][129];   // +1 pad: conflict-free column reads
  const int b = blockIdx.x;
  const int t0 = blockIdx.y * 64;
  const int tid = threadIdx.x;
#pragma unroll
  for (int c = 0; c < 8; ++c) {
    int i4 = tid + c * 256;               // 0..2047 float4 chunks of the 64x128 tile
    int row = i4 >> 5, col4 = i4 & 31;
    float4 v = ((const float4*)X)[(size_t)(b * T_ + t0 + row) * 32 + col4];
    ushort4 h;
    h.x = f2bf(v.x); h.y = f2bf(v.y); h.z = f2bf(v.z); h.w = f2bf(v.w);
    ((ushort4*)Xp)[(size_t)(b * (T_ + 2) + 1 + t0 + row) * 32 + col4] = h;
    tile[row][col4 * 4 + 0] = h.x;
    tile[row][col4 * 4 + 1] = h.y;
    tile[row][col4 * 4 + 2] = h.z;
    tile[row][col4 * 4 + 3] = h.w;
  }
  if (blockIdx.y == 0 && tid < 32) {       // zero pad rows (conv boundary)
    ushort4 z = {0, 0, 0, 0};
    ((ushort4*)Xp)[(size_t)(b * (T_ + 2) + 0) * 32 + tid] = z;
    ((ushort4*)Xp)[(size_t)(b * (T_ + 2) + T_ + 1) * 32 + tid] = z;
  }
  __syncthreads();
#pragma unroll
  for (int c = 0; c < 8; ++c) {
    int o4 = tid + c * 256;               // 0..2047 ushort4 chunks of XT tile
    int d = o4 >> 4, t4 = o4 & 15;
    ushort4 h;
    h.x = tile[t4 * 4 + 0][d];
    h.y = tile[t4 * 4 + 1][d];
    h.z = tile[t4 * 4 + 2][d];
    h.w = tile[t4 * 4 + 3][d];
    ((ushort4*)XT)[(size_t)(b * 128 + d) * (T_ / 4) + (t0 >> 2) + t4] = h;
  }
}

// ---------------- kernel 2: weights -> transposed bf16 (Wf pre-scaled by log2e/8) ----------------
__global__ __launch_bounds__(256) void prep_w(const float* __restrict__ Wf,
                                              const float* __restrict__ Wg,
                                              unsigned short* __restrict__ WfT,
                                              unsigned short* __restrict__ WgT) {
  const float SC = 0.18033688011112042f;  // (1/sqrt(64)) * log2(e)
  int idx = blockIdx.x * 256 + threadIdx.x;    // 0..32767
  if (idx < H_ * D_) {
    int h = idx >> 7, d = idx & 127;
    WfT[idx] = f2bf(Wf[d * H_ + h] * SC);
  } else {
    int j = idx - H_ * D_;                     // 0..24575
    int tap = j >> 13, r = j & 8191;
    int h = r >> 7, d = r & 127;
    WgT[j] = f2bf(Wg[tap * (D_ * H_) + d * H_ + h]);
  }
}

// ---------------- kernel 3: F = Xp[t+1]*Wf (pre-scaled), G = sum_taps Xp[t+s]*Wg[s] ----------------
__global__ __launch_bounds__(64) void fg_kernel(const unsigned short* __restrict__ Xp,
                                                const unsigned short* __restrict__ WfT,
                                                const unsigned short* __restrict__ WgT,
                                                unsigned short* __restrict__ F,
                                                unsigned short* __restrict__ G) {
  const int lane = threadIdx.x;
  const int rowbase = blockIdx.x * 64;         // global (b,t) row
  const int b = rowbase >> 12, t0 = rowbase & (T_ - 1);
  const int l15 = lane & 15, lhi = lane >> 4;
  const f32x4 fz = {0.f, 0.f, 0.f, 0.f};
  f32x4 accF[4][4], accG[4][4];
#pragma unroll
  for (int mt = 0; mt < 4; ++mt)
#pragma unroll
    for (int nt = 0; nt < 4; ++nt) { accF[mt][nt] = fz; accG[mt][nt] = fz; }

  for (int kk = 0; kk < 4; ++kk) {
    const int k0 = kk * 32 + lhi * 8;
    bf16x8 a[3][4];
#pragma unroll
    for (int sh = 0; sh < 3; ++sh)
#pragma unroll
      for (int mt = 0; mt < 4; ++mt) {
        int r = b * (T_ + 2) + t0 + sh + mt * 16 + l15;
        a[sh][mt] = *(const bf16x8*)&Xp[(size_t)r * 128 + k0];
      }
#pragma unroll
    for (int nt = 0; nt < 4; ++nt) {
      int h = nt * 16 + l15;
      bf16x8 wf  = *(const bf16x8*)&WfT[h * 128 + k0];
      bf16x8 wg0 = *(const bf16x8*)&WgT[(0 * 64 + h) * 128 + k0];
      bf16x8 wg1 = *(const bf16x8*)&WgT[(1 * 64 + h) * 128 + k0];
      bf16x8 wg2 = *(const bf16x8*)&WgT[(2 * 64 + h) * 128 + k0];
#pragma unroll
      for (int mt = 0; mt < 4; ++mt) {
        accF[mt][nt] = __builtin_amdgcn_mfma_f32_16x16x32_bf16(a[1][mt], wf,  accF[mt][nt], 0, 0, 0);
        accG[mt][nt] = __builtin_amdgcn_mfma_f32_16x16x32_bf16(a[0][mt], wg0, accG[mt][nt], 0, 0, 0);
        accG[mt][nt] = __builtin_amdgcn_mfma_f32_16x16x32_bf16(a[1][mt], wg1, accG[mt][nt], 0, 0, 0);
        accG[mt][nt] = __builtin_amdgcn_mfma_f32_16x16x32_bf16(a[2][mt], wg2, accG[mt][nt], 0, 0, 0);
      }
    }
  }
#pragma unroll
  for (int mt = 0; mt < 4; ++mt)
#pragma unroll
    for (int nt = 0; nt < 4; ++nt)
#pragma unroll
      for (int r = 0; r < 4; ++r) {
        int t = t0 + mt * 16 + lhi * 4 + r;
        int h = nt * 16 + l15;
        size_t o = (size_t)(b * T_ + t) * 64 + h;
        F[o] = f2bf(accF[mt][nt][r]);
        G[o] = f2bf(accG[mt][nt][r]);
      }
}

// ---------------- kernel 4: flash attention, Q=F K=G V=X, P=exp2(S), dbuf gload_lds ----------------
// Staging: global_load_lds writes LINEAR (base + lane*16); swizzled reads are made correct by
// pre-swizzling the GLOBAL source chunk: chunk c' = c ^ (row&7)  (rule: both-sides-or-neither).
__global__ __launch_bounds__(256) void attn_kernel(const unsigned short* __restrict__ F,
                                                   const unsigned short* __restrict__ G,
                                                   const unsigned short* __restrict__ XT,
                                                   float* __restrict__ out) {
  __shared__ unsigned short klds[2][64 * 64];    // 2 x 8KB,  [s][h] swizzled
  __shared__ unsigned short vlds[2][128 * 64];   // 2 x 16KB, [d][s] swizzled (V^T tile)
  __shared__ unsigned short plds[4][32 * 64];    // 16KB, per-wave [q][s] swizzled
  const int b = blockIdx.x;
  const int q0 = blockIdx.y * 128;
  const int tid = threadIdx.x;
  const int wave = tid >> 6, lane = tid & 63;
  const int l15 = lane & 15, lhi = lane >> 4;
  const int qw = q0 + wave * 32;

  // Q as B-operand fragments: B[n=q=l15][k=lhi*8..]
  bf16x8 qf[2][2];
#pragma unroll
  for (int nt = 0; nt < 2; ++nt)
#pragma unroll
    for (int kk = 0; kk < 2; ++kk)
      qf[nt][kk] = *(const bf16x8*)&F[(size_t)(b * T_ + qw + nt * 16 + l15) * 64 + kk * 32 + lhi * 8];

  const f32x4 fz = {0.f, 0.f, 0.f, 0.f};
  f32x4 o_acc[2][8];
  f32x4 sacc[2];
#pragma unroll
  for (int mt = 0; mt < 2; ++mt) {
    sacc[mt] = fz;
#pragma unroll
    for (int nt = 0; nt < 8; ++nt) o_acc[mt][nt] = fz;
  }
  bf16x8 ones;
#pragma unroll
  for (int j = 0; j < 8; ++j) ones[j] = (short)0x3F80;   // bf16 1.0

  char* pbase = (char*)plds[wave];
  const int lo3 = lane >> 3, lc = lane & 7;

  // stage one 64-s tile into buffer `buf` (24 issues: K 8 x 1KB, V 16 x 1KB; 6 per wave)
  auto stage = [&](int buf, int s0n) {
#pragma unroll
    for (int i = 0; i < 2; ++i) {
      int kchunk = wave * 2 + i;              // 0..7, covers rows s = kchunk*8..+8
      int s = kchunk * 8 + lo3;
      int cp = lc ^ (s & 7);                  // pre-swizzled source chunk
      async_copy16(&G[(size_t)(b * T_ + s0n + s) * 64 + cp * 8],
                   (char*)&klds[buf][0] + kchunk * 1024);
    }
#pragma unroll
    for (int i = 0; i < 4; ++i) {
      int vchunk = wave * 4 + i;              // 0..15, covers rows d = vchunk*8..+8
      int d = vchunk * 8 + lo3;
      int cp = lc ^ (d & 7);
      async_copy16(&XT[(size_t)(b * 128 + d) * T_ + s0n + cp * 8],
                   (char*)&vlds[buf][0] + vchunk * 1024);
    }
  };

  stage(0, 0);
  __syncthreads();                             // compiler drains vmcnt before barrier

  for (int t = 0; t < NT; ++t) {
    const int cur = t & 1;
    if (t + 1 < NT) stage(cur ^ 1, (t + 1) * SBLK);   // overlap next-tile DMA with compute

    char* kbase = (char*)klds[cur];
    char* vbase = (char*)vlds[cur];

    // S^T = K * Q^T (swapped operands): D[m=s][n=q]; lane holds 4 CONSECUTIVE s per frag
    f32x4 S[2][4];
#pragma unroll
    for (int st = 0; st < 4; ++st) {
      int srow = st * 16 + l15;
      bf16x8 kf0 = *(const bf16x8*)(kbase + SWZ(srow * 128 + lhi * 16, srow));
      bf16x8 kf1 = *(const bf16x8*)(kbase + SWZ(srow * 128 + 64 + lhi * 16, srow));
#pragma unroll
      for (int nt = 0; nt < 2; ++nt) {
        f32x4 s_ = fz;
        s_ = __builtin_amdgcn_mfma_f32_16x16x32_bf16(kf0, qf[nt][0], s_, 0, 0, 0);
        s_ = __builtin_amdgcn_mfma_f32_16x16x32_bf16(kf1, qf[nt][1], s_, 0, 0, 0);
        S[nt][st] = s_;
      }
    }
    // P = exp2(S^T) -> bf16 pairs -> packed b64 writes into [q][s] layout
#pragma unroll
    for (int nt = 0; nt < 2; ++nt) {
      int qrow = nt * 16 + l15;
#pragma unroll
      for (int st = 0; st < 4; ++st) {
        uint2 pk;
        pk.x = (unsigned)f2bf(__builtin_amdgcn_exp2f(S[nt][st][0]))
             | ((unsigned)f2bf(__builtin_amdgcn_exp2f(S[nt][st][1])) << 16);
        pk.y = (unsigned)f2bf(__builtin_amdgcn_exp2f(S[nt][st][2]))
             | ((unsigned)f2bf(__builtin_amdgcn_exp2f(S[nt][st][3])) << 16);
        // s-offset = st*16 + lhi*4 -> byte st*32 + lhi*8 (4 consecutive s = 8 bytes)
        *(uint2*)(pbase + SWZ(qrow * 128 + st * 32 + lhi * 8, qrow)) = pk;
      }
    }
    // reload P as A-fragments: A[m=q=l15][k=s=lhi*8..]
    bf16x8 pa[2][2];
#pragma unroll
    for (int mt = 0; mt < 2; ++mt) {
      int prow = mt * 16 + l15;
#pragma unroll
      for (int ks = 0; ks < 2; ++ks)
        pa[mt][ks] = *(const bf16x8*)(pbase + SWZ(prow * 128 + ks * 64 + lhi * 16, prow));
    }
    // row-sums via ones-fragment MFMA (accumulates l across all tiles)
#pragma unroll
    for (int mt = 0; mt < 2; ++mt) {
      sacc[mt] = __builtin_amdgcn_mfma_f32_16x16x32_bf16(pa[mt][0], ones, sacc[mt], 0, 0, 0);
      sacc[mt] = __builtin_amdgcn_mfma_f32_16x16x32_bf16(pa[mt][1], ones, sacc[mt], 0, 0, 0);
    }
    // O += P * V
#pragma unroll
    for (int nt = 0; nt < 8; ++nt) {
      int drow = nt * 16 + l15;
      bf16x8 vf0 = *(const bf16x8*)(vbase + SWZ(drow * 128 + lhi * 16, drow));
      bf16x8 vf1 = *(const bf16x8*)(vbase + SWZ(drow * 128 + 64 + lhi * 16, drow));
#pragma unroll
      for (int mt = 0; mt < 2; ++mt) {
        o_acc[mt][nt] = __builtin_amdgcn_mfma_f32_16x16x32_bf16(pa[mt][0], vf0, o_acc[mt][nt], 0, 0, 0);
        o_acc[mt][nt] = __builtin_amdgcn_mfma_f32_16x16x32_bf16(pa[mt][1], vf1, o_acc[mt][nt], 0, 0, 0);
      }
    }
    __syncthreads();   // drains the in-flight stage of buf^1, then all waves release buf[cur]
  }

  // epilogue: out = O / l  (fp32)
#pragma unroll
  for (int mt = 0; mt < 2; ++mt) {
#pragma unroll
    for (int r = 0; r < 4; ++r) {
      float inv = 1.0f / sacc[mt][r];
      int t = qw + mt * 16 + lhi * 4 + r;
#pragma unroll
      for (int nt = 0; nt < 8; ++nt)
        out[(size_t)(b * T_ + t) * 128 + nt * 16 + l15] = o_acc[mt][nt][r] * inv;
    }
  }
}

extern "C" void kernel_launch(void* const* d_in, const int* in_sizes, int n_in,
                              void* d_out, int out_size, void* d_ws, size_t ws_size,
                              hipStream_t stream) {
  (void)in_sizes; (void)n_in; (void)out_size; (void)ws_size;
  const float* X  = (const float*)d_in[0];
  const float* Wf = (const float*)d_in[1];
  const float* Wg = (const float*)d_in[2];
  float* out = (float*)d_out;
  char* ws = (char*)d_ws;
  unsigned short* Xp  = (unsigned short*)(ws + OFF_XP);
  unsigned short* XT  = (unsigned short*)(ws + OFF_XT);
  unsigned short* Fb  = (unsigned short*)(ws + OFF_F);
  unsigned short* Gb  = (unsigned short*)(ws + OFF_G);
  unsigned short* WfT = (unsigned short*)(ws + OFF_WFT);
  unsigned short* WgT = (unsigned short*)(ws + OFF_WGT);

  prep_x<<<dim3(B_, T_ / 64), 256, 0, stream>>>(X, Xp, XT);
  prep_w<<<(H_ * D_ * 4) / 256, 256, 0, stream>>>(Wf, Wg, WfT, WgT);
  fg_kernel<<<(B_ * T_) / 64, 64, 0, stream>>>(Xp, WfT, WgT, Fb, Gb);
  attn_kernel<<<dim3(B_, T_ / 128), 256, 0, stream>>>(Fb, Gb, XT, out);
}